// Round 1
// baseline (38.579 us; speedup 1.0000x reference)
//
#include <hip/hip_runtime.h>
#include <hip/hip_bf16.h>

#define LOG_2PI 1.8378770664093453f

#define NBLOCKS 2048
#define NTHREADS 256

// Kernel 1: fused elementwise + per-block reduction.
// sum over all elements of (t-m)^2/v + log(v)  -> partial[blockIdx.x]
__global__ void __launch_bounds__(NTHREADS)
nll_partial_kernel(const float* __restrict__ mean_,
                   const float* __restrict__ var_,
                   const float* __restrict__ tgt_,
                   float* __restrict__ partial,
                   int n) {
    const int nvec = n >> 2;           // float4 count
    const int tid = blockIdx.x * blockDim.x + threadIdx.x;
    const int stride = gridDim.x * blockDim.x;

    const float4* m4 = reinterpret_cast<const float4*>(mean_);
    const float4* v4 = reinterpret_cast<const float4*>(var_);
    const float4* t4 = reinterpret_cast<const float4*>(tgt_);

    float s = 0.0f;
    for (int i = tid; i < nvec; i += stride) {
        float4 m = m4[i];
        float4 v = v4[i];
        float4 t = t4[i];
        float d0 = t.x - m.x;
        float d1 = t.y - m.y;
        float d2 = t.z - m.z;
        float d3 = t.w - m.w;
        s += d0 * d0 * __frcp_rn(v.x) + __logf(v.x);
        s += d1 * d1 * __frcp_rn(v.y) + __logf(v.y);
        s += d2 * d2 * __frcp_rn(v.z) + __logf(v.z);
        s += d3 * d3 * __frcp_rn(v.w) + __logf(v.w);
    }

    // scalar tail (n % 4) — handled by global thread 0 only
    if (tid == 0) {
        for (int i = nvec << 2; i < n; ++i) {
            float d = tgt_[i] - mean_[i];
            s += d * d * __frcp_rn(var_[i]) + __logf(var_[i]);
        }
    }

    // wave-64 butterfly reduce
    #pragma unroll
    for (int off = 32; off > 0; off >>= 1)
        s += __shfl_down(s, off, 64);

    __shared__ float smem[NTHREADS / 64];
    const int wave = threadIdx.x >> 6;
    if ((threadIdx.x & 63) == 0) smem[wave] = s;
    __syncthreads();
    if (threadIdx.x == 0) {
        float b = 0.0f;
        #pragma unroll
        for (int w = 0; w < NTHREADS / 64; ++w) b += smem[w];
        partial[blockIdx.x] = b;
    }
}

// Kernel 2: deterministic final reduce of NBLOCKS partials -> scalar.
// out = total_sum / N + log(2*pi)
__global__ void __launch_bounds__(NTHREADS)
nll_final_kernel(const float* __restrict__ partial,
                 float* __restrict__ out,
                 int nb, float inv_n) {
    float s = 0.0f;
    for (int i = threadIdx.x; i < nb; i += blockDim.x)
        s += partial[i];

    #pragma unroll
    for (int off = 32; off > 0; off >>= 1)
        s += __shfl_down(s, off, 64);

    __shared__ float smem[NTHREADS / 64];
    const int wave = threadIdx.x >> 6;
    if ((threadIdx.x & 63) == 0) smem[wave] = s;
    __syncthreads();
    if (threadIdx.x == 0) {
        float b = 0.0f;
        #pragma unroll
        for (int w = 0; w < NTHREADS / 64; ++w) b += smem[w];
        out[0] = b * inv_n + LOG_2PI;
    }
}

extern "C" void kernel_launch(void* const* d_in, const int* in_sizes, int n_in,
                              void* d_out, int out_size, void* d_ws, size_t ws_size,
                              hipStream_t stream) {
    const float* mean_ = (const float*)d_in[0];
    const float* var_  = (const float*)d_in[1];
    const float* tgt_  = (const float*)d_in[2];
    float* out = (float*)d_out;
    float* partial = (float*)d_ws;   // NBLOCKS floats of scratch

    const int n = in_sizes[0];

    nll_partial_kernel<<<NBLOCKS, NTHREADS, 0, stream>>>(mean_, var_, tgt_, partial, n);
    nll_final_kernel<<<1, NTHREADS, 0, stream>>>(partial, out, NBLOCKS, 1.0f / (float)n);
}